// Round 5
// baseline (353.671 us; speedup 1.0000x reference)
//
#include <hip/hip_runtime.h>

#define DIM 64
#define NCLS 249
#define SCAN_CHUNK 1024
#define NXCD 8
#define NCHUNK 192
#define NJ 24

typedef unsigned int u32;
typedef unsigned short u16;
typedef unsigned long long u64;
using bf16x8 = __attribute__((ext_vector_type(8))) short;
using f32x4  = __attribute__((ext_vector_type(4))) float;

__device__ __forceinline__ u16 f2bf(float f) {
    u32 u = __builtin_bit_cast(u32, f);
    u += 0x7FFFu + ((u >> 16) & 1u);   // round-to-nearest-even
    return (u16)(u >> 16);
}
__device__ __forceinline__ float bf_lo(u32 u) { return __builtin_bit_cast(float, u << 16); }
__device__ __forceinline__ float bf_hi(u32 u) { return __builtin_bit_cast(float, u & 0xFFFF0000u); }

// part = d / npp via 40-bit magic (exact for d < 2^20)
__device__ __forceinline__ int part_of(int d, u64 magic) {
    return (int)(((u64)(u32)d * magic) >> 40);
}

// ---------------- zero int ----------------
__global__ void zero_i32(int* __restrict__ p, int n) {
    int i = blockIdx.x * blockDim.x + threadIdx.x;
    int stride = gridDim.x * blockDim.x;
    for (; i < n; i += stride) p[i] = 0;
}

// ---------------- pass 1: per-(chunk,part) edge counts ----------------
__global__ __launch_bounds__(256) void bucket_count(const int* __restrict__ dst, int E,
                                                    int chunk_size, u64 magic,
                                                    int* __restrict__ bcnt) {
    __shared__ int c[NXCD];
    int t = threadIdx.x;
    if (t < NXCD) c[t] = 0;
    __syncthreads();
    int base = blockIdx.x * chunk_size;
    int end = min(base + chunk_size, E);
    int l0 = 0, l1 = 0, l2 = 0, l3 = 0, l4 = 0, l5 = 0, l6 = 0, l7 = 0;
    for (int e = base + t; e < end; e += 256) {
        int p = part_of(dst[e], magic);
        l0 += (p == 0); l1 += (p == 1); l2 += (p == 2); l3 += (p == 3);
        l4 += (p == 4); l5 += (p == 5); l6 += (p == 6); l7 += (p == 7);
    }
    atomicAdd(&c[0], l0); atomicAdd(&c[1], l1);
    atomicAdd(&c[2], l2); atomicAdd(&c[3], l3);
    atomicAdd(&c[4], l4); atomicAdd(&c[5], l5);
    atomicAdd(&c[6], l6); atomicAdd(&c[7], l7);
    __syncthreads();
    if (t < NXCD) bcnt[t * NCHUNK + blockIdx.x] = c[t];   // part-major layout
}

// ---------------- exclusive scan of bcnt (part-major) -> boff, sentinel=E ----------------
__global__ __launch_bounds__(256) void scan_boff(const int* __restrict__ bcnt, int n,
                                                 int* __restrict__ boff, int total) {
    __shared__ int tmp[256];
    __shared__ int carry;
    int t = threadIdx.x;
    if (t == 0) carry = 0;
    __syncthreads();
    for (int base = 0; base < n; base += 256) {
        int v = (base + t < n) ? bcnt[base + t] : 0;
        tmp[t] = v;
        __syncthreads();
        for (int off = 1; off < 256; off <<= 1) {
            int u = (t >= off) ? tmp[t - off] : 0;
            __syncthreads();
            tmp[t] += u;
            __syncthreads();
        }
        if (base + t < n) boff[base + t] = tmp[t] - v + carry;
        __syncthreads();
        if (t == 255) carry += tmp[255];
        __syncthreads();
    }
    if (t == 0) boff[n] = total;
}

// ---------------- pass 2: scatter edges into per-part buckets ----------------
// each (chunk,part) range is exclusive to this block -> no cross-XCD line sharing
__global__ __launch_bounds__(256) void bucket_scatter(const int* __restrict__ ei, int E,
                                                      int chunk_size, u64 magic,
                                                      const int* __restrict__ boff,
                                                      u64* __restrict__ bucket) {
    __shared__ int cur[NXCD];
    int t = threadIdx.x;
    if (t < NXCD) cur[t] = boff[t * NCHUNK + blockIdx.x];
    __syncthreads();
    int base = blockIdx.x * chunk_size;
    int end = min(base + chunk_size, E);
    for (int e = base + t; e < end; e += 256) {
        int s = ei[e];
        int d = ei[E + e];
        int p = part_of(d, magic);
        int pos = atomicAdd(&cur[p], 1);
        bucket[pos] = ((u64)(u32)d << 32) | (u32)s;
    }
}

// ---------------- per-node histogram from buckets (XCD-local) ----------------
__global__ __launch_bounds__(256) void hist_bucket(const u64* __restrict__ bucket,
                                                   const int* __restrict__ boff,
                                                   int* __restrict__ cnt) {
    int p = blockIdx.x & (NXCD - 1);
    int j = blockIdx.x >> 3;
    int pa = boff[p * NCHUNK], pb = boff[(p + 1) * NCHUNK];
    int len = pb - pa;
    int beg = pa + (int)((long)len * j / NJ);
    int end = pa + (int)((long)len * (j + 1) / NJ);
    for (int i = beg + threadIdx.x; i < end; i += 256) {
        int d = (int)(bucket[i] >> 32);
        atomicAdd(&cnt[d], 1);
    }
}

__global__ __launch_bounds__(256) void scan_block_sums(const int* __restrict__ cnt, int n,
                                                       int* __restrict__ bsum) {
    __shared__ int sdata[256];
    int b = blockIdx.x, t = threadIdx.x;
    int base = b * SCAN_CHUNK;
    int s = 0;
    for (int i = t; i < SCAN_CHUNK; i += 256) {
        int idx = base + i;
        s += (idx < n) ? cnt[idx] : 0;
    }
    sdata[t] = s;
    __syncthreads();
    for (int off = 128; off > 0; off >>= 1) {
        if (t < off) sdata[t] += sdata[t + off];
        __syncthreads();
    }
    if (t == 0) bsum[b] = sdata[0];
}

__global__ __launch_bounds__(1024) void scan_bsum(int* __restrict__ bsum, int nb) {
    __shared__ int tmp[1024];
    int t = threadIdx.x;
    int v = (t < nb) ? bsum[t] : 0;
    tmp[t] = v;
    __syncthreads();
    for (int off = 1; off < 1024; off <<= 1) {
        int u = (t >= off) ? tmp[t - off] : 0;
        __syncthreads();
        tmp[t] += u;
        __syncthreads();
    }
    if (t < nb) bsum[t] = tmp[t] - v;
}

__global__ __launch_bounds__(256) void scan_final(const int* __restrict__ cnt, int n,
                                                  const int* __restrict__ bsum,
                                                  int* __restrict__ row_ptr,
                                                  int* __restrict__ cursor, int E) {
    __shared__ int tsum[256];
    int b = blockIdx.x, t = threadIdx.x;
    int base = b * SCAN_CHUNK + t * 4;
    int v[4];
    int s = 0;
#pragma unroll
    for (int i = 0; i < 4; ++i) {
        int id = base + i;
        v[i] = (id < n) ? cnt[id] : 0;
        s += v[i];
    }
    tsum[t] = s;
    __syncthreads();
    for (int off = 1; off < 256; off <<= 1) {
        int u = (t >= off) ? tsum[t - off] : 0;
        __syncthreads();
        tsum[t] += u;
        __syncthreads();
    }
    int run = tsum[t] - s + bsum[b];
#pragma unroll
    for (int i = 0; i < 4; ++i) {
        int id = base + i;
        if (id < n) { row_ptr[id] = run; cursor[id] = run; }
        run += v[i];
    }
    if (b == 0 && t == 0) row_ptr[n] = E;
}

// ---------------- CSR fill from buckets (XCD-local) ----------------
__global__ __launch_bounds__(256) void fill_bucket(const u64* __restrict__ bucket,
                                                   const int* __restrict__ boff,
                                                   int* __restrict__ cursor,
                                                   int* __restrict__ nbr) {
    int p = blockIdx.x & (NXCD - 1);
    int j = blockIdx.x >> 3;
    int pa = boff[p * NCHUNK], pb = boff[(p + 1) * NCHUNK];
    int len = pb - pa;
    int beg = pa + (int)((long)len * j / NJ);
    int end = pa + (int)((long)len * (j + 1) / NJ);
    for (int i = beg + threadIdx.x; i < end; i += 256) {
        u64 pk = bucket[i];
        int d = (int)(pk >> 32);
        int s = (int)(pk & 0xFFFFFFFFu);
        int pos = atomicAdd(&cursor[d], 1);
        nbr[pos] = s;
    }
}

// ---------------- convert x (f32) -> bf16 into A1 cols 64..127 ----------------
__global__ void convert_x(const float* __restrict__ x, u16* __restrict__ A1, int total) {
    int i = blockIdx.x * 256 + threadIdx.x;
    if (i >= total) return;
    int node = i >> 3, seg = i & 7;
    const float4 v0 = *(const float4*)(x + (size_t)i * 8);
    const float4 v1 = *(const float4*)(x + (size_t)i * 8 + 4);
    uint4 o;
    o.x = (u32)f2bf(v0.x) | ((u32)f2bf(v0.y) << 16);
    o.y = (u32)f2bf(v0.z) | ((u32)f2bf(v0.w) << 16);
    o.z = (u32)f2bf(v1.x) | ((u32)f2bf(v1.y) << 16);
    o.w = (u32)f2bf(v1.z) | ((u32)f2bf(v1.w) << 16);
    *(uint4*)(A1 + (size_t)node * 128 + 64 + seg * 8) = o;
}

// ---------------- prep weights: B[r][128] = bf16([Wl[r]|Wr[r]]) ----------------
__global__ void prep_B(const float* __restrict__ Wl, const float* __restrict__ Wr,
                       u16* __restrict__ B, int nrows_src, int nrows_dst) {
    int i = blockIdx.x * 256 + threadIdx.x;
    if (i >= nrows_dst * 128) return;
    int r = i >> 7, k = i & 127;
    float v = 0.f;
    if (r < nrows_src) v = (k < 64) ? Wl[r * 64 + k] : Wr[r * 64 + k - 64];
    B[i] = f2bf(v);
}

// ---------------- pull aggregation on bf16 panels ----------------
__global__ __launch_bounds__(256) void pull_bf16(const u16* __restrict__ Asrc,
                                                 const int* __restrict__ row_ptr,
                                                 const int* __restrict__ nbr,
                                                 u16* __restrict__ Adst, int n) {
    int tid = blockIdx.x * 256 + threadIdx.x;
    int node = tid >> 3;
    int q = tid & 7;
    if (node >= n) return;
    int beg = row_ptr[node], end = row_ptr[node + 1];
    float a0 = 0.f, a1 = 0.f, a2 = 0.f, a3 = 0.f, a4 = 0.f, a5 = 0.f, a6 = 0.f, a7 = 0.f;
    for (int j = beg; j < end; ++j) {
        int s = nbr[j];
        uint4 v = *(const uint4*)(Asrc + (size_t)s * 128 + 64 + q * 8);
        a0 += bf_lo(v.x); a1 += bf_hi(v.x);
        a2 += bf_lo(v.y); a3 += bf_hi(v.y);
        a4 += bf_lo(v.z); a5 += bf_hi(v.z);
        a6 += bf_lo(v.w); a7 += bf_hi(v.w);
    }
    uint4 o;
    o.x = (u32)f2bf(a0) | ((u32)f2bf(a1) << 16);
    o.y = (u32)f2bf(a2) | ((u32)f2bf(a3) << 16);
    o.z = (u32)f2bf(a4) | ((u32)f2bf(a5) << 16);
    o.w = (u32)f2bf(a6) | ((u32)f2bf(a7) << 16);
    *(uint4*)(Adst + (size_t)node * 128 + q * 8) = o;
}

// ---------------- MFMA GEMM: [64 nodes] x [NT*16 cols], K=128 ----------------
template<int NT, bool RELU, bool OUT_BF16>
__global__ __launch_bounds__(256) void gemm_kernel(
    const u16* __restrict__ A, const u16* __restrict__ B,
    const float* __restrict__ bias,
    float* __restrict__ outf, u16* __restrict__ outb,
    int n_nodes, int n_cols)
{
    constexpr int KC = (NT == 16) ? 2 : 1;
    constexpr int KW = 128 / KC;
    constexpr int RG = KW / 8;
    constexpr int NR = NT * 16;
    __shared__ uint4 A_lds[64 * 16];
    __shared__ uint4 B_lds[2048];

    const int t = threadIdx.x;
    const int node0 = blockIdx.x * 64;

#pragma unroll
    for (int i = 0; i < 4; ++i) {
        int gl = t + 256 * i;
        int r = gl >> 4, g = gl & 15;
        uint4 v = make_uint4(0u, 0u, 0u, 0u);
        int node = node0 + r;
        if (node < n_nodes) v = *(const uint4*)(A + (size_t)node * 128 + g * 8);
        A_lds[r * 16 + (g ^ (r & 7))] = v;
    }

    const int w  = t >> 6;
    const int l  = t & 63;
    const int lm = l & 15;
    const int lg = l >> 4;
    const int arow = w * 16 + lm;
    const int asw  = arow & 7;

    f32x4 acc[NT];
#pragma unroll
    for (int n = 0; n < NT; ++n) acc[n] = f32x4{0.f, 0.f, 0.f, 0.f};

#pragma unroll
    for (int kc = 0; kc < KC; ++kc) {
        __syncthreads();
#pragma unroll
        for (int i = 0; i < (NR * RG) / 256; ++i) {
            int gl = t + 256 * i;
            int r = gl / RG, g = gl % RG;
            uint4 v = *(const uint4*)(B + (size_t)r * 128 + kc * KW + g * 8);
            B_lds[r * RG + (g ^ (r & 7))] = v;
        }
        __syncthreads();
#pragma unroll
        for (int ks = 0; ks < KW / 32; ++ks) {
            int ag = lg + (kc * (KW / 32) + ks) * 4;
            bf16x8 af = __builtin_bit_cast(bf16x8, A_lds[arow * 16 + (ag ^ asw)]);
#pragma unroll
            for (int n = 0; n < NT; ++n) {
                int brow = n * 16 + lm;
                int bg = lg + ks * 4;
                bf16x8 bf = __builtin_bit_cast(bf16x8, B_lds[brow * RG + (bg ^ (brow & 7))]);
                acc[n] = __builtin_amdgcn_mfma_f32_16x16x32_bf16(af, bf, acc[n], 0, 0, 0);
            }
        }
    }

    const int rbase = w * 16 + lg * 4;
#pragma unroll
    for (int n = 0; n < NT; ++n) {
        int c = n * 16 + lm;
        float bv = (c < n_cols) ? bias[c] : 0.f;
#pragma unroll
        for (int r = 0; r < 4; ++r) {
            int node = node0 + rbase + r;
            if (node < n_nodes && c < n_cols) {
                float v = acc[n][r] + bv;
                if (RELU) v = fmaxf(v, 0.f);
                if (OUT_BF16) outb[(size_t)node * 128 + 64 + c] = f2bf(v);
                else outf[(size_t)node * (size_t)n_cols + c] = v;
            }
        }
    }
}

extern "C" void kernel_launch(void* const* d_in, const int* in_sizes, int n_in,
                              void* d_out, int out_size, void* d_ws, size_t ws_size,
                              hipStream_t stream) {
    const float* x   = (const float*)d_in[0];
    const int*   ei  = (const int*)d_in[1];
    const float* W1l = (const float*)d_in[2];
    const float* b1  = (const float*)d_in[3];
    const float* W1r = (const float*)d_in[4];
    const float* W2l = (const float*)d_in[5];
    const float* b2  = (const float*)d_in[6];
    const float* W2r = (const float*)d_in[7];
    float* out = (float*)d_out;

    const int N = in_sizes[0] / DIM;     // 100000
    const int E = in_sizes[1] / 2;       // 1600000
    const int NPAD = ((N + 63) / 64) * 64;
    const int NB = (N + SCAN_CHUNK - 1) / SCAN_CHUNK;

    // workspace layout
    char* wp = (char*)d_ws;
    u16* A1 = (u16*)wp;                 wp += (size_t)NPAD * 128 * 2;
    u16* A2 = (u16*)wp;                 wp += (size_t)NPAD * 128 * 2;
    u16* B1 = (u16*)wp;                 wp += 64 * 128 * 2;
    u16* B2 = (u16*)wp;                 wp += 256 * 128 * 2;
    int* cnt     = (int*)wp;            wp += (size_t)N * 4;
    int* row_ptr = (int*)wp;            wp += (size_t)(N + 1) * 4;
    int* cursor  = (int*)wp;            wp += (size_t)N * 4;
    int* bsum    = (int*)wp;            wp += 1024 * 4;
    int* bcnt    = (int*)wp;            wp += NXCD * NCHUNK * 4;
    int* boff    = (int*)wp;            wp += (NXCD * NCHUNK + 1) * 4;
    int* nbr     = (int*)wp;
    // bucket aliases A2: dead before gemm1 writes A2 (fill completes first)
    u64* bucket  = (u64*)A2;

    const int npp = (N + NXCD - 1) / NXCD;             // 12500
    const u64 magic = ((1ull << 40) + npp - 1) / npp;  // exact div for d < 2^20
    const int chunk_size = (E + NCHUNK - 1) / NCHUNK;

    // ---- CSR build (radix-partitioned) ----
    zero_i32<<<512, 256, 0, stream>>>(cnt, N);
    bucket_count<<<NCHUNK, 256, 0, stream>>>(ei + E, E, chunk_size, magic, bcnt);
    scan_boff<<<1, 256, 0, stream>>>(bcnt, NXCD * NCHUNK, boff, E);
    bucket_scatter<<<NCHUNK, 256, 0, stream>>>(ei, E, chunk_size, magic, boff, bucket);
    hist_bucket<<<NJ * NXCD, 256, 0, stream>>>(bucket, boff, cnt);
    scan_block_sums<<<NB, 256, 0, stream>>>(cnt, N, bsum);
    scan_bsum<<<1, 1024, 0, stream>>>(bsum, NB);
    scan_final<<<NB, 256, 0, stream>>>(cnt, N, bsum, row_ptr, cursor, E);
    fill_bucket<<<NJ * NXCD, 256, 0, stream>>>(bucket, boff, cursor, nbr);

    // ---- conversions / weight prep ----
    convert_x<<<(N * 8 + 255) / 256, 256, 0, stream>>>(x, A1, N * 8);
    prep_B<<<(64 * 128 + 255) / 256, 256, 0, stream>>>(W1l, W1r, B1, 64, 64);
    prep_B<<<(256 * 128 + 255) / 256, 256, 0, stream>>>(W2l, W2r, B2, NCLS, 256);

    const int gemm_blocks = NPAD / 64;

    // ---- layer 1 ----
    pull_bf16<<<(N * 8 + 255) / 256, 256, 0, stream>>>(A1, row_ptr, nbr, A1, N);
    gemm_kernel<4, true, true><<<gemm_blocks, 256, 0, stream>>>(A1, B1, b1, nullptr, A2, N, 64);

    // ---- layer 2 ----
    pull_bf16<<<(N * 8 + 255) / 256, 256, 0, stream>>>(A2, row_ptr, nbr, A2, N);
    gemm_kernel<16, false, false><<<gemm_blocks, 256, 0, stream>>>(A2, B2, b2, out, nullptr, N, NCLS);
}